// Round 1
// baseline (227.930 us; speedup 1.0000x reference)
//
#include <hip/hip_runtime.h>
#include <hip/hip_bf16.h>
#include <math.h>

// Problem constants (from reference)
#define NB 8
#define NT 1024
#define NF 80
#define NSTACK 4
#define NSTRIDE 4
#define NG 4
#define NE 16
#define NC 8192
#define ND 512
#define NTS 256          // (NT-NSTACK)/NSTRIDE + 1
#define NP (NB*NTS)      // 2048 subsampled positions
#define SFD (NSTACK*NF)  // 320
#define FREG 0.01f
#define LNEPS 1e-5f

// k_logits tiling
#define TCC 1024   // c columns per block
#define CPT 4      // c per thread (float4)
#define PCH 16     // active positions per chunk (LDS-staged)
#define PB 16      // grid z (chunk parallelism)

struct Ws {
  float penSum;
  unsigned int nA;
  unsigned int maskIsInt;
  unsigned int pad1;
  unsigned long long amax[NP*NG];  // packed (key<<32 | ~idx) argmax
  float sumExp[NP*NG];
  float tLogit[NP*NG];
  int   targets[NP*NG];
  int   activeList[NP];
  unsigned int bitmap[NC/32];
};

// ---- detect whether masks buffer is uint8 (numpy bool) or int32 ----
// Reads only first 8192 bytes (valid under both layouts). int32-encoded 0/1
// has zero bytes at all offsets %4 != 0; uint8 masks (runs of 10 ones) do not.
__global__ void k_detect(const unsigned char* __restrict__ m, Ws* ws) {
  __shared__ unsigned flag;
  if (threadIdx.x == 0) flag = 0;
  __syncthreads();
  unsigned nz = 0;
  int base = threadIdx.x * 32;
  for (int i = base; i < base + 32; ++i)
    if ((i & 3) && m[i]) nz = 1;
  if (nz) atomicOr(&flag, 1u);
  __syncthreads();
  if (threadIdx.x == 0) ws->maskIsInt = (flag ? 0u : 1u);
}

// ---- features_pen = mean(((feats-mean)*istd)^2) over all B*T*F ----
__global__ void k_pen(const float* __restrict__ feats,
                      const float* __restrict__ mean,
                      const float* __restrict__ istd, Ws* ws) {
  const int N4 = NB*NT*NF/4;
  float s = 0.f;
  for (int i = blockIdx.x*blockDim.x + threadIdx.x; i < N4; i += gridDim.x*blockDim.x) {
    float4 v = reinterpret_cast<const float4*>(feats)[i];
    int f0 = (i*4) % NF;   // NF%4==0 -> quad stays within one feature row
    float x0 = (v.x - mean[f0+0]) * istd[f0+0];
    float x1 = (v.y - mean[f0+1]) * istd[f0+1];
    float x2 = (v.z - mean[f0+2]) * istd[f0+2];
    float x3 = (v.w - mean[f0+3]) * istd[f0+3];
    s += x0*x0 + x1*x1 + x2*x2 + x3*x3;
  }
  for (int o = 32; o; o >>= 1) s += __shfl_down(s, o);
  if ((threadIdx.x & 63) == 0) atomicAdd(&ws->penSum, s);
}

// ---- m[b,ts] = all(masks window) & (ts < lens_sub) ; compact actives ----
__global__ void k_mask(const unsigned char* __restrict__ m8,
                       const int* __restrict__ lens, Ws* ws) {
  int p = blockIdx.x*blockDim.x + threadIdx.x;
  if (p >= NP) return;
  int b = p >> 8, ts = p & (NTS-1);
  int t0 = b*NT + ts*NSTRIDE;
  bool allm;
  if (ws->maskIsInt) {
    const int* m32 = (const int*)m8;
    allm = m32[t0] && m32[t0+1] && m32[t0+2] && m32[t0+3];
  } else {
    allm = m8[t0] && m8[t0+1] && m8[t0+2] && m8[t0+3];
  }
  int ls = (lens[b] - NSTACK)/NSTRIDE + 1;   // lens >= 512 so positive
  if (ls < 0) ls = 0;
  if (allm && ts < ls) {
    unsigned idx = atomicAdd(&ws->nA, 1u);
    ws->activeList[idx] = p;
  }
}

// ---- per active position: stack, LayerNorm, project, argmin-quantize ----
__global__ __launch_bounds__(256) void k_quant(
    const float* __restrict__ feats, const float* __restrict__ mean,
    const float* __restrict__ istd, const float* __restrict__ projw,
    const float* __restrict__ emb, Ws* ws) {
  if (blockIdx.x >= ws->nA) return;
  int ai = blockIdx.x;
  int p = ws->activeList[ai];
  int b = p >> 8, ts = p & (NTS-1);
  int tid = threadIdx.x;
  __shared__ float sN[SFD];
  __shared__ float sPart[4*64];
  __shared__ float sLat[NG*NE];
  __shared__ float sRedS[256];
  __shared__ int   sRedC[256];
  __shared__ float rS[4], rQ[4];
  __shared__ int   sTgt[NG];

  for (int j = tid; j < SFD; j += 256) {
    int k = j / NF, f = j - k*NF;
    sN[j] = (feats[((size_t)b*NT + ts*NSTRIDE + k)*NF + f] - mean[f]) * istd[f];
  }
  __syncthreads();
  float s = 0.f, q = 0.f;
  for (int j = tid; j < SFD; j += 256) { float x = sN[j]; s += x; q += x*x; }
  for (int o = 32; o; o >>= 1) { s += __shfl_down(s, o); q += __shfl_down(q, o); }
  if ((tid & 63) == 0) { rS[tid>>6] = s; rQ[tid>>6] = q; }
  __syncthreads();
  float mu  = (rS[0]+rS[1]+rS[2]+rS[3]) * (1.f/SFD);
  float var = (rQ[0]+rQ[1]+rQ[2]+rQ[3]) * (1.f/SFD) - mu*mu;
  float inv = rsqrtf(var + LNEPS);
  for (int j = tid; j < SFD; j += 256) sN[j] = (sN[j]-mu)*inv;
  __syncthreads();
  {
    int j = tid & 63, part = tid >> 6;   // 4 parts x 80 rows
    float a = 0.f;
    int i0 = part*80;
    for (int i = i0; i < i0+80; ++i) a = fmaf(sN[i], projw[i*64 + j], a);
    sPart[part*64 + j] = a;
  }
  __syncthreads();
  if (tid < 64) sLat[tid] = sPart[tid] + sPart[64+tid] + sPart[128+tid] + sPart[192+tid];
  __syncthreads();

  for (int g = 0; g < NG; ++g) {
    float lg[NE];
    #pragma unroll
    for (int e = 0; e < NE; ++e) lg[e] = sLat[g*NE + e];
    float best = 3.4e38f; int bc = NC;
    for (int c = tid; c < NC; c += 256) {
      const float4* cb4 = reinterpret_cast<const float4*>(emb + ((size_t)c*NG + g)*NE);
      float4 a0 = cb4[0], a1 = cb4[1], a2 = cb4[2], a3 = cb4[3];
      float dot = 0.f, n2 = 0.f;
      dot = fmaf(lg[0],  a0.x, dot); n2 = fmaf(a0.x, a0.x, n2);
      dot = fmaf(lg[1],  a0.y, dot); n2 = fmaf(a0.y, a0.y, n2);
      dot = fmaf(lg[2],  a0.z, dot); n2 = fmaf(a0.z, a0.z, n2);
      dot = fmaf(lg[3],  a0.w, dot); n2 = fmaf(a0.w, a0.w, n2);
      dot = fmaf(lg[4],  a1.x, dot); n2 = fmaf(a1.x, a1.x, n2);
      dot = fmaf(lg[5],  a1.y, dot); n2 = fmaf(a1.y, a1.y, n2);
      dot = fmaf(lg[6],  a1.z, dot); n2 = fmaf(a1.z, a1.z, n2);
      dot = fmaf(lg[7],  a1.w, dot); n2 = fmaf(a1.w, a1.w, n2);
      dot = fmaf(lg[8],  a2.x, dot); n2 = fmaf(a2.x, a2.x, n2);
      dot = fmaf(lg[9],  a2.y, dot); n2 = fmaf(a2.y, a2.y, n2);
      dot = fmaf(lg[10], a2.z, dot); n2 = fmaf(a2.z, a2.z, n2);
      dot = fmaf(lg[11], a2.w, dot); n2 = fmaf(a2.w, a2.w, n2);
      dot = fmaf(lg[12], a3.x, dot); n2 = fmaf(a3.x, a3.x, n2);
      dot = fmaf(lg[13], a3.y, dot); n2 = fmaf(a3.y, a3.y, n2);
      dot = fmaf(lg[14], a3.z, dot); n2 = fmaf(a3.z, a3.z, n2);
      dot = fmaf(lg[15], a3.w, dot); n2 = fmaf(a3.w, a3.w, n2);
      float sc = n2 - 2.f*dot;        // |lat|^2 constant per g -> dropped
      if (sc < best) { best = sc; bc = c; }   // ascending c: first-min kept
    }
    sRedS[tid] = best; sRedC[tid] = bc;
    __syncthreads();
    for (int off = 128; off; off >>= 1) {
      if (tid < off) {
        float os = sRedS[tid+off]; int oc = sRedC[tid+off];
        if (os < sRedS[tid] || (os == sRedS[tid] && oc < sRedC[tid])) {
          sRedS[tid] = os; sRedC[tid] = oc;
        }
      }
      __syncthreads();
    }
    if (tid == 0) sTgt[g] = sRedC[0];
    __syncthreads();
  }
  if (tid < NG) {
    int c = sTgt[tid];
    ws->targets[ai*NG + tid] = c;
    atomicOr(&ws->bitmap[c >> 5], 1u << (c & 31));
  }
}

// ---- logits GEMM restricted to active rows + logsumexp/argmax/target ----
__global__ __launch_bounds__(256) void k_logits(
    const float* __restrict__ W, const float* __restrict__ bias,
    const float* __restrict__ enc, Ws* ws) {
  const int nA = (int)ws->nA;
  if (nA == 0) return;
  const int nCh = (nA + PCH - 1) / PCH;
  const int g = blockIdx.y;
  const int cbase = blockIdx.x * TCC + threadIdx.x * CPT;
  const float* __restrict__ Wg = W + (size_t)g*ND*NC;
  const float b0 = bias[g*NC + cbase + 0];
  const float b1 = bias[g*NC + cbase + 1];
  const float b2 = bias[g*NC + cbase + 2];
  const float b3 = bias[g*NC + cbase + 3];
  __shared__ float4 sEnc[PCH][ND/4];   // 32 KB
  __shared__ int sP[PCH];

  for (int ch = blockIdx.z; ch < nCh; ch += PB) {
    if (threadIdx.x < PCH) {
      int ai = ch*PCH + threadIdx.x;
      sP[threadIdx.x] = (ai < nA) ? ws->activeList[ai] : -1;
    }
    __syncthreads();
    for (int i = threadIdx.x; i < PCH*(ND/4); i += 256) {
      int qq = i >> 7, r = i & 127;
      int p = sP[qq];
      sEnc[qq][r] = (p >= 0) ? reinterpret_cast<const float4*>(enc)[p*(ND/4) + r]
                             : make_float4(0.f, 0.f, 0.f, 0.f);
    }
    __syncthreads();

    float acc[PCH][CPT];
    #pragma unroll
    for (int qq = 0; qq < PCH; ++qq) {
      #pragma unroll
      for (int j = 0; j < CPT; ++j) acc[qq][j] = 0.f;
    }
    for (int d = 0; d < ND; d += 4) {
      const float* wp = Wg + (size_t)d*NC + cbase;
      float4 w0 = *reinterpret_cast<const float4*>(wp);
      float4 w1 = *reinterpret_cast<const float4*>(wp + NC);
      float4 w2 = *reinterpret_cast<const float4*>(wp + 2*NC);
      float4 w3 = *reinterpret_cast<const float4*>(wp + 3*NC);
      int dq = d >> 2;
      #pragma unroll
      for (int qq = 0; qq < PCH; ++qq) {
        float4 e = sEnc[qq][dq];       // uniform address -> LDS broadcast
        acc[qq][0] = fmaf(e.x, w0.x, acc[qq][0]);
        acc[qq][1] = fmaf(e.x, w0.y, acc[qq][1]);
        acc[qq][2] = fmaf(e.x, w0.z, acc[qq][2]);
        acc[qq][3] = fmaf(e.x, w0.w, acc[qq][3]);
        acc[qq][0] = fmaf(e.y, w1.x, acc[qq][0]);
        acc[qq][1] = fmaf(e.y, w1.y, acc[qq][1]);
        acc[qq][2] = fmaf(e.y, w1.z, acc[qq][2]);
        acc[qq][3] = fmaf(e.y, w1.w, acc[qq][3]);
        acc[qq][0] = fmaf(e.z, w2.x, acc[qq][0]);
        acc[qq][1] = fmaf(e.z, w2.y, acc[qq][1]);
        acc[qq][2] = fmaf(e.z, w2.z, acc[qq][2]);
        acc[qq][3] = fmaf(e.z, w2.w, acc[qq][3]);
        acc[qq][0] = fmaf(e.w, w3.x, acc[qq][0]);
        acc[qq][1] = fmaf(e.w, w3.y, acc[qq][1]);
        acc[qq][2] = fmaf(e.w, w3.z, acc[qq][2]);
        acc[qq][3] = fmaf(e.w, w3.w, acc[qq][3]);
      }
    }

    #pragma unroll
    for (int qq = 0; qq < PCH; ++qq) {
      int ai = ch*PCH + qq;
      if (ai < nA) {
        float l0 = acc[qq][0] + b0;
        float l1 = acc[qq][1] + b1;
        float l2 = acc[qq][2] + b2;
        float l3 = acc[qq][3] + b3;
        int tgt = ws->targets[ai*NG + g];
        if ((unsigned)(tgt - cbase) < (unsigned)CPT) {   // unique writer
          float tv = (tgt == cbase) ? l0 : (tgt == cbase+1) ? l1
                   : (tgt == cbase+2) ? l2 : l3;
          ws->tLogit[ai*NG + g] = tv;
        }
        float es = expf(l0) + expf(l1) + expf(l2) + expf(l3);
        float mv = l0; int mi = cbase;
        if (l1 > mv) { mv = l1; mi = cbase+1; }
        if (l2 > mv) { mv = l2; mi = cbase+2; }
        if (l3 > mv) { mv = l3; mi = cbase+3; }
        for (int o = 32; o; o >>= 1) {
          es += __shfl_down(es, o);
          float ov = __shfl_down(mv, o);
          int   oi = __shfl_down(mi, o);
          if (ov > mv || (ov == mv && oi < mi)) { mv = ov; mi = oi; }
        }
        if ((threadIdx.x & 63) == 0) {
          atomicAdd(&ws->sumExp[ai*NG + g], es);
          unsigned key = __float_as_uint(mv);
          key = (key & 0x80000000u) ? ~key : (key | 0x80000000u);
          unsigned long long pk =
              ((unsigned long long)key << 32) |
              (unsigned long long)(0xFFFFFFFFu - (unsigned)mi);
          atomicMax(&ws->amax[ai*NG + g], pk);
        }
      }
    }
    __syncthreads();
  }
}

// ---- final scalar assembly ----
__global__ __launch_bounds__(256) void k_final(Ws* ws, float* __restrict__ out) {
  int tid = threadIdx.x;
  int nA = (int)ws->nA;
  float sumPer = 0.f, sumCorr = 0.f;
  for (int i = tid; i < nA*NG; i += 256) {
    sumPer += logf(ws->sumExp[i]) - ws->tLogit[i];   // per = -(logp at target)
    unsigned long long pk = ws->amax[i];
    int mi = (int)(0xFFFFFFFFu - (unsigned)(pk & 0xFFFFFFFFull));
    if (mi == ws->targets[i]) sumCorr += 1.f;
  }
  unsigned w = ws->bitmap[tid];
  if (tid == 0 && nA < NP) w |= 1u;   // masked positions contribute code 0
  int uniq = __popc(w);

  __shared__ float rs[4], rc[4]; __shared__ int ru[4];
  float s1 = sumPer, s2 = sumCorr; int s3 = uniq;
  for (int o = 32; o; o >>= 1) {
    s1 += __shfl_down(s1, o);
    s2 += __shfl_down(s2, o);
    s3 += __shfl_down(s3, o);
  }
  if ((tid & 63) == 0) { rs[tid>>6] = s1; rc[tid>>6] = s2; ru[tid>>6] = s3; }
  __syncthreads();
  if (tid == 0) {
    float sp = rs[0]+rs[1]+rs[2]+rs[3];
    float sc = rc[0]+rc[1]+rc[2]+rc[3];
    int   un = ru[0]+ru[1]+ru[2]+ru[3];
    float pen   = ws->penSum / (float)(NB*NT*NF);
    float denom = (float)nA + 1e-5f;
    float nc    = (float)(nA * NG);
    out[0] = sp / (denom * (float)NG) + FREG * pen;
    out[1] = sc / nc;
    out[2] = pen;
    out[3] = nc;
    out[4] = (float)un;
  }
}

extern "C" void kernel_launch(void* const* d_in, const int* in_sizes, int n_in,
                              void* d_out, int out_size, void* d_ws, size_t ws_size,
                              hipStream_t stream) {
  const float* feats = (const float*)d_in[0];
  const int*   lens  = (const int*)d_in[1];
  const unsigned char* masks = (const unsigned char*)d_in[2];
  // d_in[3] mask_emb: unused (only feeds the delegated encoder)
  const float* mean  = (const float*)d_in[4];
  const float* istd  = (const float*)d_in[5];
  const float* projw = (const float*)d_in[6];
  const float* emb   = (const float*)d_in[7];
  const float* W     = (const float*)d_in[8];
  const float* bias  = (const float*)d_in[9];
  const float* enc   = (const float*)d_in[10];
  Ws* ws = (Ws*)d_ws;
  float* out = (float*)d_out;

  hipMemsetAsync(d_ws, 0, sizeof(Ws), stream);
  k_detect<<<1, 256, 0, stream>>>(masks, ws);
  k_pen<<<256, 256, 0, stream>>>(feats, mean, istd, ws);
  k_mask<<<NP/256, 256, 0, stream>>>(masks, lens, ws);
  k_quant<<<NP, 256, 0, stream>>>(feats, mean, istd, projw, emb, ws);
  k_logits<<<dim3(NC/TCC, NG, PB), 256, 0, stream>>>(W, bias, enc, ws);
  k_final<<<1, 256, 0, stream>>>(ws, out);
}